// Round 3
// baseline (388.075 us; speedup 1.0000x reference)
//
#include <hip/hip_runtime.h>
#include <math.h>

#define B 32
#define C 512
#define H 56
#define W 56
#define HW (H * W)      // 3136
#define HW4 (HW / 4)    // 784
#define W4 (W / 4)      // 14
#define KD 768

#define BH 4                   // output rows per block (band)
#define NBAND (H / BH)         // 14
#define HR (BH + 6)            // 10 halo rows
#define NP4 (HR * W4)          // 140 pooled float4 positions
#define GPOOL 4                // channel groups for pooling partials
#define CPG (C / GPOOL)        // 128
#define NITEM (NP4 * GPOOL)    // 560

typedef float floatx4 __attribute__((ext_vector_type(4)));

// Single self-contained kernel. Block = (batch b, 4-row band).
//   A) conv weights + bias dot (768 FMA) while zeroing the padded conv-input LDS
//   B) pool the 10-row halo window over ALL 512 channels directly from x
//      (2.5x read amplification; x is L3-resident so HBM sees it ~once)
//   C) reduce 4 channel-group partials -> zero-padded [2][10][62] maps in LDS
//   D) 7x7 conv + keyword bias + sigmoid -> 224 scales in LDS
//   E) stream 512 ch x 4 rows: out = x * scale (regular loads keep x in L3
//      for neighbor blocks' halo reads; NT stores stream out past caches)
// No workspace, no inter-block dependency, one launch.
__global__ __launch_bounds__(256) void spatial_gate_kernel(
    const float* __restrict__ x, const float* __restrict__ keyword,
    const float* __restrict__ conv_w, const float* __restrict__ conv_b,
    const float* __restrict__ proj_w, const float* __restrict__ proj_b,
    float* __restrict__ out) {

    __shared__ floatx4 p_max[GPOOL][NP4];          // 8.96 KB
    __shared__ floatx4 p_sum[GPOOL][NP4];          // 8.96 KB
    __shared__ float sm[2][HR][62];                // 4.96 KB zero-padded maps
    __shared__ float s_w[100];                     // conv weights + conv_b + proj_b
    __shared__ __align__(16) float s_scale[BH * W];
    __shared__ float s_red[4];

    const int tid  = threadIdx.x;
    const int band = blockIdx.x % NBAND;
    const int b    = blockIdx.x / NBAND;
    const int row0 = band * BH;

    // --- Phase A ---
    if (tid < 98) s_w[tid] = conv_w[tid];
    if (tid == 98) s_w[98] = conv_b[0];
    if (tid == 99) s_w[99] = proj_b[0];

    for (int i = tid; i < 2 * HR * 62; i += 256) ((float*)sm)[i] = 0.f;

    float part = keyword[b * KD + tid]       * proj_w[tid]
               + keyword[b * KD + tid + 256] * proj_w[tid + 256]
               + keyword[b * KD + tid + 512] * proj_w[tid + 512];
    #pragma unroll
    for (int off = 32; off > 0; off >>= 1)
        part += __shfl_down(part, off);
    if ((tid & 63) == 0) s_red[tid >> 6] = part;

    // --- Phase B: pool partials over the halo window ---
    const floatx4* xb = (const floatx4*)x + (size_t)b * C * HW4;
    for (int idx = tid; idx < NITEM; idx += 256) {
        const int g    = idx / NP4;
        const int pos4 = idx - g * NP4;
        const int r    = pos4 / W4;
        const int j    = pos4 - r * W4;
        const int ih   = row0 - 3 + r;
        if (ih < 0 || ih >= H) continue;           // halo rows stay zero
        const floatx4* p = xb + (size_t)(g * CPG) * HW4 + ih * W4 + j;
        floatx4 mx = { -INFINITY, -INFINITY, -INFINITY, -INFINITY };
        floatx4 ac = { 0.f, 0.f, 0.f, 0.f };
        #pragma unroll 4
        for (int c = 0; c < CPG; ++c) {
            floatx4 v = p[(size_t)c * HW4];
            mx.x = fmaxf(mx.x, v.x); mx.y = fmaxf(mx.y, v.y);
            mx.z = fmaxf(mx.z, v.z); mx.w = fmaxf(mx.w, v.w);
            ac += v;
        }
        p_max[g][pos4] = mx;
        p_sum[g][pos4] = ac;
    }
    __syncthreads();

    // --- Phase C: reduce channel groups -> zero-padded conv-input maps ---
    if (tid < NP4) {
        const int r  = tid / W4;
        const int j  = tid - r * W4;
        const int ih = row0 - 3 + r;
        if (ih >= 0 && ih < H) {
            floatx4 mx = p_max[0][tid];
            floatx4 ac = p_sum[0][tid];
            #pragma unroll
            for (int g = 1; g < GPOOL; ++g) {
                floatx4 m2 = p_max[g][tid];
                mx.x = fmaxf(mx.x, m2.x); mx.y = fmaxf(mx.y, m2.y);
                mx.z = fmaxf(mx.z, m2.z); mx.w = fmaxf(mx.w, m2.w);
                ac += p_sum[g][tid];
            }
            const floatx4 mn = ac * (1.0f / (float)C);
            #pragma unroll
            for (int e = 0; e < 4; ++e) {
                sm[0][r][3 + 4 * j + e] = mx[e];
                sm[1][r][3 + 4 * j + e] = mn[e];
            }
        }
    }
    __syncthreads();

    // --- Phase D: conv + bias + sigmoid ---
    if (tid < BH * W) {
        const int dr  = tid / W;
        const int col = tid - dr * W;
        float acc = s_red[0] + s_red[1] + s_red[2] + s_red[3] + s_w[98] + s_w[99];
        #pragma unroll
        for (int kh = 0; kh < 7; ++kh) {
            #pragma unroll
            for (int kw = 0; kw < 7; ++kw) {
                acc = fmaf(sm[0][dr + kh][col + kw], s_w[kh * 7 + kw],
                      fmaf(sm[1][dr + kh][col + kw], s_w[49 + kh * 7 + kw], acc));
            }
        }
        s_scale[tid] = 1.0f / (1.0f + __expf(-acc));
    }
    __syncthreads();

    // --- Phase E: stream out = x * scale (512 ch x 56 float4) ---
    const floatx4* s4   = (const floatx4*)s_scale;  // 56 entries
    const floatx4* x4   = (const floatx4*)x;
    floatx4*       out4 = (floatx4*)out;
    const int base = b * C * HW4 + row0 * W4;       // + cl*HW4 + f
    int cl = tid / 56;
    int f  = tid - cl * 56;
    #pragma unroll 4
    for (int k = 0; k < (C * BH * W4) / 256; ++k) { // 112 iterations
        const int g = base + cl * HW4 + f;
        floatx4 xv = x4[g];
        floatx4 ov = xv * s4[f];
        __builtin_nontemporal_store(ov, &out4[g]);
        // advance flat index by 256: (dcl,df) = (4,+32) or (5,-24)
        const int fn = f + 32;
        const int wrap = (fn >= 56);
        f  = wrap ? fn - 56 : fn;
        cl = cl + 4 + wrap;
    }
}

extern "C" void kernel_launch(void* const* d_in, const int* in_sizes, int n_in,
                              void* d_out, int out_size, void* d_ws, size_t ws_size,
                              hipStream_t stream) {
    const float* x       = (const float*)d_in[0];
    const float* keyword = (const float*)d_in[1];
    const float* conv_w  = (const float*)d_in[2];
    const float* conv_b  = (const float*)d_in[3];
    const float* proj_w  = (const float*)d_in[4];
    const float* proj_b  = (const float*)d_in[5];
    float* out = (float*)d_out;

    spatial_gate_kernel<<<B * NBAND, 256, 0, stream>>>(
        x, keyword, conv_w, conv_b, proj_w, proj_b, out);
}